// Round 5
// baseline (65.366 us; speedup 1.0000x reference)
//
#include <hip/hip_runtime.h>

#define VOCAB 32000
#define EMB   1024
#define TPB   512
#define COLS  64                  // vocab cols per tile: 256B read granule
#define TILES (VOCAB / COLS)      // 500
#define CH    128                 // emb rows per LDS chunk (512B store granule)
#define NCHUNK 4                  // chunks per row-group
#define RG_ROWS 512               // rows per row-group (2 row-groups cover EMB)
#define CAP_T 512                 // per-tile bucket capacity (expected ~65)

typedef float f32x4 __attribute__((ext_vector_type(4)));

// ---------------------------------------------------------------------------
// Pass 0: zero per-tile counters (d_ws is poisoned, not zeroed).
// ---------------------------------------------------------------------------
__global__ __launch_bounds__(TPB) void tok_emb_zero(int* __restrict__ cnt) {
    const int i = blockIdx.x * TPB + threadIdx.x;
    if (i < TILES) cnt[i] = 0;
}

// ---------------------------------------------------------------------------
// Pass 1: bucket tokens by 64-wide vocab tile.
// ---------------------------------------------------------------------------
__global__ __launch_bounds__(TPB) void tok_emb_bucket(
    const int* __restrict__ tokens, int* __restrict__ cnt,
    int* __restrict__ bucket, int n_tokens) {
    const int i4 = (blockIdx.x * TPB + threadIdx.x) * 4;
    if (i4 + 3 < n_tokens) {
        const int4 tk = *reinterpret_cast<const int4*>(&tokens[i4]);
        const int tv[4] = {tk.x, tk.y, tk.z, tk.w};
#pragma unroll
        for (int j = 0; j < 4; ++j) {
            const unsigned tile = (unsigned)tv[j] >> 6;
            if (tile < TILES) {
                const int p = atomicAdd(&cnt[tile], 1);
                if (p < CAP_T) bucket[tile * CAP_T + p] = ((i4 + j) << 6) | (tv[j] & 63);
            }
        }
    } else {
        for (int i = i4; i < n_tokens; ++i) {
            const unsigned tile = (unsigned)tokens[i] >> 6;
            if (tile < TILES) {
                const int p = atomicAdd(&cnt[tile], 1);
                if (p < CAP_T) bucket[tile * CAP_T + p] = (i << 6) | (tokens[i] & 63);
            }
        }
    }
}

// ---------------------------------------------------------------------------
// Pass 2: block = (tile, row-group). Stage W[c0:c0+128, v0:v0+64] transposed
// + XOR-swizzled in LDS; per matched token stream 512B nt-store segments.
// LDS dword addr = col*128 + (r ^ (((col>>2)&7)<<2)):
//   staging writes: 2 lanes/bank (free); token reads: conflict-free b128.
// Pipeline: next chunk's global loads issued before current store phase.
// ---------------------------------------------------------------------------
__global__ __launch_bounds__(TPB) void tok_emb_main(
    const float* __restrict__ W, const int* __restrict__ tokens,
    const int* __restrict__ cnt, const int* __restrict__ bucket,
    f32x4* __restrict__ out4, int n_tokens) {
    __shared__ float lds[COLS * CH];    // 32 KB
    __shared__ int   list[CAP_T];       // 2 KB
    __shared__ int   scnt;

    const int tile  = blockIdx.x >> 1;
    const int rg    = blockIdx.x & 1;
    const int v0    = tile * COLS;
    const int rbase = rg * RG_ROWS;
    const int tid   = threadIdx.x;

    const int rr  = tid >> 4;           // base row within chunk (0..31)
    const int ccg = (tid & 15) << 2;    // col group base (0,4,..,60)
    const int swz = (tid & 7) << 2;     // write swizzle = ((col>>2)&7)<<2

    const float* wbase = W + (size_t)v0 + (size_t)ccg;

    auto process = [&](int m) {
        if (m == 0) return;
        f32x4 ra, rb, rc, rd;
        auto issue = [&](int c0) {
            const float* p = wbase + (size_t)(c0 + rr) * VOCAB;
            ra = *reinterpret_cast<const f32x4*>(p);
            rb = *reinterpret_cast<const f32x4*>(p + (size_t)32 * VOCAB);
            rc = *reinterpret_cast<const f32x4*>(p + (size_t)64 * VOCAB);
            rd = *reinterpret_cast<const f32x4*>(p + (size_t)96 * VOCAB);
        };
        issue(rbase);
        for (int ch = 0; ch < NCHUNK; ++ch) {
            const int c0 = rbase + ch * CH;
            // regs -> LDS (transpose scatter, swizzled)
            {
                const int s0 = (rr +  0) ^ swz;
                const int s1 = (rr + 32) ^ swz;
                const int s2 = (rr + 64) ^ swz;
                const int s3 = (rr + 96) ^ swz;
#pragma unroll
                for (int j = 0; j < 4; ++j) lds[(ccg + j) * CH + s0] = ra[j];
#pragma unroll
                for (int j = 0; j < 4; ++j) lds[(ccg + j) * CH + s1] = rb[j];
#pragma unroll
                for (int j = 0; j < 4; ++j) lds[(ccg + j) * CH + s2] = rc[j];
#pragma unroll
                for (int j = 0; j < 4; ++j) lds[(ccg + j) * CH + s3] = rd[j];
            }
            __syncthreads();
            if (ch + 1 < NCHUNK) issue(rbase + (ch + 1) * CH);  // overlap w/ stores
            // store phase: conflict-free b128 LDS reads + 512B nt segments
            const int nst = m << 5;     // m tokens * 32 float4
            for (int j = tid; j < nst; j += TPB) {
                const int ent  = list[j >> 5];
                const int lane = j & 31;
                const int t    = ent >> 6;
                const int col  = ent & 63;
                const int cp   = (col >> 2) & 7;
                const f32x4 v  = *reinterpret_cast<const f32x4*>(
                    lds + col * CH + ((lane ^ cp) << 2));
                __builtin_nontemporal_store(
                    v, &out4[(size_t)t * (EMB / 4) + (c0 >> 2) + lane]);
            }
            __syncthreads();            // readers done before next LDS write
        }
    };

    const int m_total = (bucket != nullptr) ? cnt[tile] : CAP_T + 1;
    if (m_total <= CAP_T) {
        for (int j = tid; j < m_total; j += TPB) list[j] = bucket[tile * CAP_T + j];
        process(m_total);               // first barrier inside covers list
    } else {
        // Structural backstop: segmented scan, CAP_T tokens per segment.
        for (int lo = 0; lo < n_tokens; lo += CAP_T) {
            const int hi = (lo + CAP_T < n_tokens) ? lo + CAP_T : n_tokens;
            __syncthreads();
            if (tid == 0) scnt = 0;
            __syncthreads();
            for (int i = lo + tid; i < hi; i += TPB) {
                const unsigned d = (unsigned)(tokens[i] - v0);
                if (d < COLS) {
                    const int p = atomicAdd(&scnt, 1);
                    list[p] = (i << 6) | (int)d;
                }
            }
            __syncthreads();
            process(scnt);
        }
    }
}

extern "C" void kernel_launch(void* const* d_in, const int* in_sizes, int n_in,
                              void* d_out, int out_size, void* d_ws, size_t ws_size,
                              hipStream_t stream) {
    const int*   tokens   = (const int*)d_in[0];   // [8*4096] int32
    const float* W        = (const float*)d_in[1]; // [1024][32000] f32
    f32x4*       out4     = (f32x4*)d_out;         // [32768][1024] f32
    const int    n_tokens = in_sizes[0];

    const size_t need = (size_t)TILES * sizeof(int)
                      + (size_t)TILES * CAP_T * sizeof(int);
    if (ws_size >= need) {
        int* cnt    = (int*)d_ws;
        int* bucket = cnt + TILES;
        tok_emb_zero<<<1, TPB, 0, stream>>>(cnt);
        const int quads = (n_tokens + 3) / 4;
        tok_emb_bucket<<<(quads + TPB - 1) / TPB, TPB, 0, stream>>>(
            tokens, cnt, bucket, n_tokens);
        tok_emb_main<<<TILES * 2, TPB, 0, stream>>>(
            W, tokens, cnt, bucket, out4, n_tokens);
    } else {
        tok_emb_main<<<TILES * 2, TPB, 0, stream>>>(
            W, tokens, nullptr, nullptr, out4, n_tokens);
    }
}

// Round 6
// 60.553 us; speedup vs baseline: 1.0795x; 1.0795x over previous
//
#include <hip/hip_runtime.h>

#define VOCAB 32000
#define EMB   1024
#define TPB   512
#define COLS  32                  // vocab cols per tile = one 128B line per W row
#define TILES (VOCAB / COLS)      // 1000
#define CH    512                 // emb rows per chunk -> 2KB contiguous stores
#define NCHUNK (EMB / CH)         // 2
#define CAP_T 256                 // per-tile bucket capacity (expected ~33)

typedef float f32x4 __attribute__((ext_vector_type(4)));

// ---------------------------------------------------------------------------
// Pass 0: zero per-tile counters (d_ws is poisoned, not zeroed).
// ---------------------------------------------------------------------------
__global__ __launch_bounds__(TPB) void tok_emb_zero(int* __restrict__ cnt) {
    const int i = blockIdx.x * TPB + threadIdx.x;
    if (i < TILES) cnt[i] = 0;
}

// ---------------------------------------------------------------------------
// Pass 1: bucket tokens by 32-wide vocab tile.
// ---------------------------------------------------------------------------
__global__ __launch_bounds__(TPB) void tok_emb_bucket(
    const int* __restrict__ tokens, int* __restrict__ cnt,
    int* __restrict__ bucket, int n_tokens) {
    const int i4 = (blockIdx.x * TPB + threadIdx.x) * 4;
    if (i4 + 3 < n_tokens) {
        const int4 tk = *reinterpret_cast<const int4*>(&tokens[i4]);
        const int tv[4] = {tk.x, tk.y, tk.z, tk.w};
#pragma unroll
        for (int j = 0; j < 4; ++j) {
            const unsigned tile = (unsigned)tv[j] >> 5;
            if (tile < TILES) {
                const int p = atomicAdd(&cnt[tile], 1);
                if (p < CAP_T) bucket[tile * CAP_T + p] = ((i4 + j) << 5) | (tv[j] & 31);
            }
        }
    } else {
        for (int i = i4; i < n_tokens; ++i) {
            const unsigned tile = (unsigned)tokens[i] >> 5;
            if (tile < TILES) {
                const int p = atomicAdd(&cnt[tile], 1);
                if (p < CAP_T) bucket[tile * CAP_T + p] = (i << 5) | (tokens[i] & 31);
            }
        }
    }
}

// ---------------------------------------------------------------------------
// Pass 2: one block per 32-col vocab tile. Stage W[c0:c0+512, v0:v0+32]
// transposed + XOR-swizzled in 64KB LDS; per matched token emit one 2KB
// contiguous nt-store segment per chunk.
//   LDS dword addr = col*512 + (row ^ ((col>>2)<<2))
//   staging writes: exactly 2 lanes/bank (free)
//   token reads: aligned conflict-free ds_read_b128 (swizzle only in row
//   bits 2-4, float4 stays consecutive)
// Chunk-1 global loads are issued before chunk-0's store phase (T14).
// ---------------------------------------------------------------------------
__global__ __launch_bounds__(TPB) void tok_emb_main(
    const float* __restrict__ W, const int* __restrict__ tokens,
    const int* __restrict__ cnt, const int* __restrict__ bucket,
    f32x4* __restrict__ out4, int n_tokens) {
    __shared__ float lds[COLS * CH];   // 64 KB
    __shared__ int   list[CAP_T];      // 1 KB
    __shared__ int   scnt;

    const int tile = blockIdx.x;
    const int v0   = tile * COLS;
    const int tid  = threadIdx.x;

    const int cg  = tid & 7;           // col group (4 floats); also swizzle key
    const int rb  = tid >> 3;          // row base 0..63
    const int swz = cg << 2;           // row-XOR bits 2-4

    const float* wbase = W + (size_t)v0 + (size_t)(cg << 2);

    f32x4 r[8];
    auto issue = [&](int c0) {         // 8 x 128B full-line loads per thread
#pragma unroll
        for (int k = 0; k < 8; ++k)
            r[k] = *reinterpret_cast<const f32x4*>(
                wbase + (size_t)(c0 + rb + (k << 6)) * VOCAB);
    };
    auto commit = [&]() {              // regs -> LDS transpose scatter
#pragma unroll
        for (int k = 0; k < 8; ++k) {
            const int rs = (rb + (k << 6)) ^ swz;
#pragma unroll
            for (int j = 0; j < 4; ++j)
                lds[(((cg << 2) + j) << 9) + rs] = r[k][j];
        }
    };

    auto process = [&](int m) {
        if (m == 0) return;
        issue(0);
        commit();
        __syncthreads();               // also covers list[] writes
        for (int ch = 0; ch < NCHUNK; ++ch) {
            if (ch + 1 < NCHUNK) issue((ch + 1) * CH);  // overlap w/ stores
            const int c0  = ch * CH;
            const int nst = m << 7;    // m tokens * 128 float4
            for (int j = tid; j < nst; j += TPB) {
                const int ent = list[j >> 7];
                const int i   = j & 127;
                const int t   = ent >> 5;
                const int c   = ent & 31;
                const f32x4 v = *reinterpret_cast<const f32x4*>(
                    lds + (c << 9) + ((i << 2) ^ ((c >> 2) << 2)));
                __builtin_nontemporal_store(
                    v, &out4[(size_t)t * (EMB / 4) + (c0 >> 2) + i]);
            }
            __syncthreads();           // readers done
            if (ch + 1 < NCHUNK) {
                commit();
                __syncthreads();
            }
        }
    };

    const int m_total = (bucket != nullptr) ? cnt[tile] : CAP_T + 1;
    if (m_total <= CAP_T) {
        for (int j = tid; j < m_total; j += TPB)
            list[j] = bucket[tile * CAP_T + j];
        process(m_total);              // first barrier inside covers list
    } else {
        // Structural backstop: segmented scan, CAP_T tokens per segment.
        for (int lo = 0; lo < n_tokens; lo += CAP_T) {
            const int hi = (lo + CAP_T < n_tokens) ? lo + CAP_T : n_tokens;
            __syncthreads();
            if (tid == 0) scnt = 0;
            __syncthreads();
            for (int i = lo + tid; i < hi; i += TPB) {
                const unsigned d = (unsigned)(tokens[i] - v0);
                if (d < COLS) {
                    const int p = atomicAdd(&scnt, 1);
                    list[p] = (i << 5) | (int)d;
                }
            }
            __syncthreads();
            process(scnt);
        }
    }
}

extern "C" void kernel_launch(void* const* d_in, const int* in_sizes, int n_in,
                              void* d_out, int out_size, void* d_ws, size_t ws_size,
                              hipStream_t stream) {
    const int*   tokens   = (const int*)d_in[0];   // [8*4096] int32
    const float* W        = (const float*)d_in[1]; // [1024][32000] f32
    f32x4*       out4     = (f32x4*)d_out;         // [32768][1024] f32
    const int    n_tokens = in_sizes[0];

    const size_t need = (size_t)TILES * sizeof(int)
                      + (size_t)TILES * CAP_T * sizeof(int);
    if (ws_size >= need) {
        int* cnt    = (int*)d_ws;
        int* bucket = cnt + TILES;
        tok_emb_zero<<<(TILES + TPB - 1) / TPB, TPB, 0, stream>>>(cnt);
        const int quads = (n_tokens + 3) / 4;
        tok_emb_bucket<<<(quads + TPB - 1) / TPB, TPB, 0, stream>>>(
            tokens, cnt, bucket, n_tokens);
        tok_emb_main<<<TILES, TPB, 0, stream>>>(
            W, tokens, cnt, bucket, out4, n_tokens);
    } else {
        tok_emb_main<<<TILES, TPB, 0, stream>>>(
            W, tokens, nullptr, nullptr, out4, n_tokens);
    }
}